// Round 1
// baseline (502.860 us; speedup 1.0000x reference)
//
#include <hip/hip_runtime.h>

#define D_MODEL 2048
#define QKVC 2304
#define DH 128
#define NH 16
#define BATCH 2
#define SEQ 2048
#define MROWS (BATCH*SEQ)   // 4096

typedef __attribute__((ext_vector_type(4))) float f32x4;
typedef __attribute__((ext_vector_type(8))) short s16x8;
typedef __attribute__((ext_vector_type(8))) __bf16 bf16x8;

static __device__ __forceinline__ unsigned short f2bf(float f) {
  unsigned int u = __builtin_bit_cast(unsigned int, f);
  u += 0x7fff + ((u >> 16) & 1);   // round-to-nearest-even
  return (unsigned short)(u >> 16);
}

static __device__ __forceinline__ f32x4 mfma16(s16x8 a, s16x8 b, f32x4 c) {
  return __builtin_amdgcn_mfma_f32_16x16x32_bf16(
      __builtin_bit_cast(bf16x8, a), __builtin_bit_cast(bf16x8, b), c, 0, 0, 0);
}

typedef const __attribute__((address_space(1))) void gvoid_t;
typedef __attribute__((address_space(3))) void svoid_t;

static __device__ __forceinline__ void gload_lds16(const void* g, void* l) {
  __builtin_amdgcn_global_load_lds((gvoid_t*)g, (svoid_t*)l, 16, 0, 0);
}

// ---------------- fp32 -> bf16 elementwise (x) ----------------
__global__ void cvt_bf16_kernel(const float* __restrict__ in,
                                unsigned short* __restrict__ out, int n4) {
  int i = blockIdx.x * blockDim.x + threadIdx.x;
  int stride = gridDim.x * blockDim.x;
  for (int idx = i; idx < n4; idx += stride) {
    float4 v = ((const float4*)in)[idx];
    ushort4 o;
    o.x = f2bf(v.x); o.y = f2bf(v.y); o.z = f2bf(v.z); o.w = f2bf(v.w);
    ((ushort4*)out)[idx] = o;
  }
}

// ------------- transpose+convert: f32 [R][C] -> bf16 [C][R] -------------
__global__ void transpose_cvt_kernel(const float* __restrict__ in,
                                     unsigned short* __restrict__ out,
                                     int R, int C) {
  __shared__ float tile[32][33];
  int c0 = blockIdx.x * 32, r0 = blockIdx.y * 32;
  int tx = threadIdx.x, ty = threadIdx.y;
#pragma unroll
  for (int i = 0; i < 4; ++i)
    tile[ty + i*8][tx] = in[(size_t)(r0 + ty + i*8) * C + c0 + tx];
  __syncthreads();
#pragma unroll
  for (int i = 0; i < 4; ++i)
    out[(size_t)(c0 + ty + i*8) * R + r0 + tx] = f2bf(tile[tx][ty + i*8]);
}

// ------------- transpose V: VT[b][d][s] = qkv[b*S+s][2176+d] -------------
__global__ void transpose_v_kernel(const unsigned short* __restrict__ qkv,
                                   unsigned short* __restrict__ VT) {
  __shared__ unsigned short tile[32][33];
  int s0 = blockIdx.x * 32, d0 = blockIdx.y * 32, b = blockIdx.z;
  int tx = threadIdx.x, ty = threadIdx.y;
#pragma unroll
  for (int i = 0; i < 4; ++i)
    tile[ty + i*8][tx] =
        qkv[(size_t)(b*SEQ + s0 + ty + i*8) * QKVC + (D_MODEL + DH) + d0 + tx];
  __syncthreads();
#pragma unroll
  for (int i = 0; i < 4; ++i)
    VT[(size_t)(b*DH + d0 + ty + i*8) * SEQ + s0 + tx] = tile[tx][ty + i*8];
}

// ------------- GEMM: C[M,N] = A[M,K](bf16) * BT[N,K]^T(bf16) + bias -------------
// 128x128 tile, BK=32, 4 waves (2x2), 16x16x32 MFMA, global_load_lds staging.
template<int OUT_F32>
__global__ __launch_bounds__(256, 2)
void gemm_bt_kernel(const unsigned short* __restrict__ A,
                    const unsigned short* __restrict__ BT,
                    const float* __restrict__ bias,
                    void* __restrict__ Cout,
                    int M, int N, int K) {
  __shared__ unsigned short Al[128*32];
  __shared__ unsigned short Bl[128*32];
  int tid = threadIdx.x;
  int lane = tid & 63, wave = tid >> 6;
  int m0 = blockIdx.y * 128, n0 = blockIdx.x * 128;
  int wr = wave >> 1, wc = wave & 1;
  int fr = lane & 15, fq = lane >> 4;
  f32x4 acc[4][4] = {};

  int c0 = wave * 2;
  int kcol = (lane & 3) * 8;          // bf16 elements within row
  int rsub = (lane >> 2);             // 0..15

  for (int k0 = 0; k0 < K; k0 += 32) {
#pragma unroll
    for (int i = 0; i < 2; ++i) {
      int c = c0 + i;
      int row = c*16 + rsub;
      gload_lds16(A  + (size_t)(m0 + row)*K + k0 + kcol, (char*)Al + c*1024);
      gload_lds16(BT + (size_t)(n0 + row)*K + k0 + kcol, (char*)Bl + c*1024);
    }
    __syncthreads();
    s16x8 af[4], bfr[4];
#pragma unroll
    for (int m = 0; m < 4; ++m)
      af[m] = *(const s16x8*)&Al[(wr*64 + m*16 + fr)*32 + fq*8];
#pragma unroll
    for (int n = 0; n < 4; ++n)
      bfr[n] = *(const s16x8*)&Bl[(wc*64 + n*16 + fr)*32 + fq*8];
#pragma unroll
    for (int m = 0; m < 4; ++m)
#pragma unroll
      for (int n = 0; n < 4; ++n)
        acc[m][n] = mfma16(af[m], bfr[n], acc[m][n]);
    __syncthreads();
  }

#pragma unroll
  for (int n = 0; n < 4; ++n) {
    int col = n0 + wc*64 + n*16 + fr;
    float bv = bias[col];
#pragma unroll
    for (int m = 0; m < 4; ++m) {
      int rowb = m0 + wr*64 + m*16 + fq*4;
#pragma unroll
      for (int j = 0; j < 4; ++j) {
        float v = acc[m][n][j] + bv;
        if (OUT_F32) ((float*)Cout)[(size_t)(rowb + j)*N + col] = v;
        else ((unsigned short*)Cout)[(size_t)(rowb + j)*N + col] = f2bf(v);
      }
    }
  }
}

// ------------- causal MQA attention -------------
// 1 wave / 16 q-rows. KV blocks of 32. qkv: [B*S][2304] bf16 (q|k|v),
// VT: [B][128][S] bf16. O: [B*S][2048] bf16 (row = b*S+s, col = h*128+d).
__global__ __launch_bounds__(64)
void mqa_attn_kernel(const unsigned short* __restrict__ qkv,
                     const unsigned short* __restrict__ VT,
                     unsigned short* __restrict__ O) {
  int qt = blockIdx.x, h = blockIdx.y, b = blockIdx.z;
  int lane = threadIdx.x;
  int fr = lane & 15, fq = lane >> 4;
  int q0 = qt * 16;
  const float scale = 0.08838834764831845f;  // 1/sqrt(128)
  __shared__ unsigned short P_lds[16*32];

  // Q fragments (A-operand): row = fr, k = ks*32 + fq*8 + 0..7
  s16x8 qf[4];
  {
    const unsigned short* qb =
        qkv + (size_t)(b*SEQ + q0 + fr)*QKVC + h*DH + fq*8;
#pragma unroll
    for (int ks = 0; ks < 4; ++ks) qf[ks] = *(const s16x8*)(qb + ks*32);
  }

  f32x4 oacc[8] = {};
  float m_r[4], l_r[4];
#pragma unroll
  for (int j = 0; j < 4; ++j) { m_r[j] = -3.0e38f; l_r[j] = 0.f; }

  int nkb = (q0 + 16 + 31) >> 5;  // causal bound
  for (int kb = 0; kb < nkb; ++kb) {
    int kv0 = kb * 32;
    f32x4 sfr[2] = {};
#pragma unroll
    for (int nt = 0; nt < 2; ++nt) {
      const unsigned short* kbp =
          qkv + (size_t)(b*SEQ + kv0 + nt*16 + fr)*QKVC + D_MODEL + fq*8;
#pragma unroll
      for (int ks = 0; ks < 4; ++ks)
        sfr[nt] = mfma16(qf[ks], *(const s16x8*)(kbp + ks*32), sfr[nt]);
    }
    // scale + causal mask (C layout: col = kv0+nt*16+fr, row = q0+fq*4+j)
    bool need_mask = (kv0 + 31 > q0);
#pragma unroll
    for (int nt = 0; nt < 2; ++nt) {
      int col = kv0 + nt*16 + fr;
#pragma unroll
      for (int j = 0; j < 4; ++j) {
        float v = sfr[nt][j] * scale;
        int row = q0 + fq*4 + j;
        if (need_mask && col > row) v = -1.0e30f;
        sfr[nt][j] = v;
      }
    }
    // online softmax: row reduce across the 16 lanes of each group
    float fac[4];
#pragma unroll
    for (int j = 0; j < 4; ++j) {
      float pm = fmaxf(sfr[0][j], sfr[1][j]);
#pragma unroll
      for (int msk = 1; msk < 16; msk <<= 1)
        pm = fmaxf(pm, __shfl_xor(pm, msk, 16));
      float mnew = fmaxf(m_r[j], pm);
      fac[j] = __expf(m_r[j] - mnew);
      m_r[j] = mnew;
      float p0 = __expf(sfr[0][j] - mnew);
      float p1 = __expf(sfr[1][j] - mnew);
      sfr[0][j] = p0; sfr[1][j] = p1;
      float rs = p0 + p1;
#pragma unroll
      for (int msk = 1; msk < 16; msk <<= 1)
        rs += __shfl_xor(rs, msk, 16);
      l_r[j] = l_r[j] * fac[j] + rs;
    }
#pragma unroll
    for (int n2 = 0; n2 < 8; ++n2)
#pragma unroll
      for (int j = 0; j < 4; ++j) oacc[n2][j] *= fac[j];

    // P (C layout) -> LDS -> A-operand layout
#pragma unroll
    for (int nt = 0; nt < 2; ++nt)
#pragma unroll
      for (int j = 0; j < 4; ++j)
        P_lds[(fq*4 + j)*32 + nt*16 + fr] = f2bf(sfr[nt][j]);
    __syncthreads();
    s16x8 pa = *(const s16x8*)&P_lds[fr*32 + fq*8];

    // PV: B-operand from VT (contiguous in kv)
#pragma unroll
    for (int n2 = 0; n2 < 8; ++n2) {
      s16x8 vf = *(const s16x8*)(VT + (size_t)(b*DH + n2*16 + fr)*SEQ + kv0 + fq*8);
      oacc[n2] = mfma16(pa, vf, oacc[n2]);
    }
    __syncthreads();
  }

  float inv[4];
#pragma unroll
  for (int j = 0; j < 4; ++j) inv[j] = 1.0f / l_r[j];
#pragma unroll
  for (int n2 = 0; n2 < 8; ++n2) {
    int col = h*DH + n2*16 + fr;
#pragma unroll
    for (int j = 0; j < 4; ++j) {
      int row = q0 + fq*4 + j;
      O[(size_t)(b*SEQ + row)*D_MODEL + col] = f2bf(oacc[n2][j] * inv[j]);
    }
  }
}

extern "C" void kernel_launch(void* const* d_in, const int* in_sizes, int n_in,
                              void* d_out, int out_size, void* d_ws, size_t ws_size,
                              hipStream_t stream) {
  const float* x     = (const float*)d_in[0];
  const float* W_qkv = (const float*)d_in[1];
  const float* b_qkv = (const float*)d_in[2];
  const float* W_out = (const float*)d_in[3];
  const float* b_out = (const float*)d_in[4];
  float* out = (float*)d_out;

  unsigned short* x_bf = (unsigned short*)d_ws;
  unsigned short* WqT  = x_bf + (size_t)MROWS * D_MODEL;
  unsigned short* WoT  = WqT  + (size_t)QKVC * D_MODEL;
  unsigned short* qkvb = WoT  + (size_t)D_MODEL * D_MODEL;
  unsigned short* VTb  = qkvb + (size_t)MROWS * QKVC;
  unsigned short* Ob   = VTb  + (size_t)BATCH * DH * SEQ;
  // total ws use: ~71.3 MB

  dim3 tb(32, 8);
  cvt_bf16_kernel<<<2048, 256, 0, stream>>>(x, x_bf, (MROWS * D_MODEL) / 4);
  transpose_cvt_kernel<<<dim3(QKVC/32, D_MODEL/32), tb, 0, stream>>>(W_qkv, WqT, D_MODEL, QKVC);
  transpose_cvt_kernel<<<dim3(D_MODEL/32, D_MODEL/32), tb, 0, stream>>>(W_out, WoT, D_MODEL, D_MODEL);

  gemm_bt_kernel<0><<<dim3(QKVC/128, MROWS/128), 256, 0, stream>>>(
      x_bf, WqT, b_qkv, qkvb, MROWS, QKVC, D_MODEL);

  transpose_v_kernel<<<dim3(SEQ/32, DH/32, BATCH), tb, 0, stream>>>(qkvb, VTb);

  mqa_attn_kernel<<<dim3(SEQ/16, NH, BATCH), 64, 0, stream>>>(qkvb, VTb, Ob);

  gemm_bt_kernel<1><<<dim3(D_MODEL/128, MROWS/128), 256, 0, stream>>>(
      Ob, WoT, b_out, out, MROWS, D_MODEL, D_MODEL);
}

// Round 2
// 307.327 us; speedup vs baseline: 1.6362x; 1.6362x over previous
//
#include <hip/hip_runtime.h>

#define D_MODEL 2048
#define QKVC 2304
#define DH 128
#define NH 16
#define BATCH 2
#define SEQ 2048
#define MROWS (BATCH*SEQ)   // 4096

typedef __attribute__((ext_vector_type(4))) float f32x4;
typedef __attribute__((ext_vector_type(8))) short s16x8;
typedef __attribute__((ext_vector_type(8))) __bf16 bf16x8;

static __device__ __forceinline__ unsigned short f2bf(float f) {
  unsigned int u = __builtin_bit_cast(unsigned int, f);
  u += 0x7fff + ((u >> 16) & 1);   // round-to-nearest-even
  return (unsigned short)(u >> 16);
}

static __device__ __forceinline__ f32x4 mfma16(s16x8 a, s16x8 b, f32x4 c) {
  return __builtin_amdgcn_mfma_f32_16x16x32_bf16(
      __builtin_bit_cast(bf16x8, a), __builtin_bit_cast(bf16x8, b), c, 0, 0, 0);
}

typedef const __attribute__((address_space(1))) void gvoid_t;
typedef __attribute__((address_space(3))) void svoid_t;

static __device__ __forceinline__ void gload_lds16(const void* g, void* l) {
  __builtin_amdgcn_global_load_lds((gvoid_t*)g, (svoid_t*)l, 16, 0, 0);
}

// ---------------- fp32 -> bf16 elementwise (x) ----------------
__global__ void cvt_bf16_kernel(const float* __restrict__ in,
                                unsigned short* __restrict__ out, int n4) {
  int i = blockIdx.x * blockDim.x + threadIdx.x;
  int stride = gridDim.x * blockDim.x;
  for (int idx = i; idx < n4; idx += stride) {
    float4 v = ((const float4*)in)[idx];
    ushort4 o;
    o.x = f2bf(v.x); o.y = f2bf(v.y); o.z = f2bf(v.z); o.w = f2bf(v.w);
    ((ushort4*)out)[idx] = o;
  }
}

// ------------- transpose+convert: f32 [R][C] -> bf16 [C][R] -------------
__global__ void transpose_cvt_kernel(const float* __restrict__ in,
                                     unsigned short* __restrict__ out,
                                     int R, int C) {
  __shared__ float tile[32][33];
  int c0 = blockIdx.x * 32, r0 = blockIdx.y * 32;
  int tx = threadIdx.x, ty = threadIdx.y;
#pragma unroll
  for (int i = 0; i < 4; ++i)
    tile[ty + i*8][tx] = in[(size_t)(r0 + ty + i*8) * C + c0 + tx];
  __syncthreads();
#pragma unroll
  for (int i = 0; i < 4; ++i)
    out[(size_t)(c0 + ty + i*8) * R + r0 + tx] = f2bf(tile[tx][ty + i*8]);
}

// ------------- transpose V: VT[b][d][s] = qkv[b*S+s][2176+d] -------------
__global__ void transpose_v_kernel(const unsigned short* __restrict__ qkv,
                                   unsigned short* __restrict__ VT) {
  __shared__ unsigned short tile[32][33];
  int s0 = blockIdx.x * 32, d0 = blockIdx.y * 32, b = blockIdx.z;
  int tx = threadIdx.x, ty = threadIdx.y;
#pragma unroll
  for (int i = 0; i < 4; ++i)
    tile[ty + i*8][tx] =
        qkv[(size_t)(b*SEQ + s0 + ty + i*8) * QKVC + (D_MODEL + DH) + d0 + tx];
  __syncthreads();
#pragma unroll
  for (int i = 0; i < 4; ++i)
    VT[(size_t)(b*DH + d0 + ty + i*8) * SEQ + s0 + tx] = tile[tx][ty + i*8];
}

// ------------- GEMM: C[M,N] = A[M,K](bf16) * BT[N,K]^T(bf16) + bias -------------
template<int OUT_F32>
__global__ __launch_bounds__(256, 2)
void gemm_bt_kernel(const unsigned short* __restrict__ A,
                    const unsigned short* __restrict__ BT,
                    const float* __restrict__ bias,
                    void* __restrict__ Cout,
                    int M, int N, int K) {
  __shared__ unsigned short Al[128*32];
  __shared__ unsigned short Bl[128*32];
  int tid = threadIdx.x;
  int lane = tid & 63, wave = tid >> 6;
  int m0 = blockIdx.y * 128, n0 = blockIdx.x * 128;
  int wr = wave >> 1, wc = wave & 1;
  int fr = lane & 15, fq = lane >> 4;
  f32x4 acc[4][4] = {};

  int c0 = wave * 2;
  int kcol = (lane & 3) * 8;
  int rsub = (lane >> 2);

  for (int k0 = 0; k0 < K; k0 += 32) {
#pragma unroll
    for (int i = 0; i < 2; ++i) {
      int c = c0 + i;
      int row = c*16 + rsub;
      gload_lds16(A  + (size_t)(m0 + row)*K + k0 + kcol, (char*)Al + c*1024);
      gload_lds16(BT + (size_t)(n0 + row)*K + k0 + kcol, (char*)Bl + c*1024);
    }
    __syncthreads();
    s16x8 af[4], bfr[4];
#pragma unroll
    for (int m = 0; m < 4; ++m)
      af[m] = *(const s16x8*)&Al[(wr*64 + m*16 + fr)*32 + fq*8];
#pragma unroll
    for (int n = 0; n < 4; ++n)
      bfr[n] = *(const s16x8*)&Bl[(wc*64 + n*16 + fr)*32 + fq*8];
#pragma unroll
    for (int m = 0; m < 4; ++m)
#pragma unroll
      for (int n = 0; n < 4; ++n)
        acc[m][n] = mfma16(af[m], bfr[n], acc[m][n]);
    __syncthreads();
  }

#pragma unroll
  for (int n = 0; n < 4; ++n) {
    int col = n0 + wc*64 + n*16 + fr;
    float bv = bias[col];
#pragma unroll
    for (int m = 0; m < 4; ++m) {
      int rowb = m0 + wr*64 + m*16 + fq*4;
#pragma unroll
      for (int j = 0; j < 4; ++j) {
        float v = acc[m][n][j] + bv;
        if (OUT_F32) ((float*)Cout)[(size_t)(rowb + j)*N + col] = v;
        else ((unsigned short*)Cout)[(size_t)(rowb + j)*N + col] = f2bf(v);
      }
    }
  }
}

// ------------- causal MQA attention, 4-wave blocks, LDS-staged K/V -------------
// Block: 256 threads = 4 waves; handles QBLK=64 q-rows of one (b,h).
// Wave w owns q rows q0 = qt*64 + w*16 .. +15. KVBLK=64.
// K tile [64][128] bf16 and VT tile [128][64] bf16 staged via global_load_lds,
// XOR-swizzled (16B chunk index ^= row&7) via pre-swizzled global source.
__global__ __launch_bounds__(256)
void mqa_attn_kernel(const unsigned short* __restrict__ qkv,
                     const unsigned short* __restrict__ VT,
                     unsigned short* __restrict__ O) {
  __shared__ unsigned short Kl[64*128];    // 16 KB
  __shared__ unsigned short Vl[128*64];    // 16 KB
  __shared__ unsigned short Pl[4*16*72];   // 9 KB (72-elem row stride: 2-way max)
  int qt = (gridDim.x - 1) - blockIdx.x;   // longest blocks first
  int h = blockIdx.y, b = blockIdx.z;
  int tid = threadIdx.x;
  int lane = tid & 63, w = tid >> 6;
  int fr = lane & 15, fq = lane >> 4;
  int q0 = qt*64 + w*16;
  const float scale = 0.08838834764831845f;  // 1/sqrt(128)

  unsigned short* Pw = Pl + w*16*72;

  // Q fragments (A-operand): row = fr, k = ks*32 + fq*8 + 0..7
  s16x8 qf[4];
  {
    const unsigned short* qb =
        qkv + (size_t)(b*SEQ + q0 + fr)*QKVC + h*DH + fq*8;
#pragma unroll
    for (int ks = 0; ks < 4; ++ks) qf[ks] = *(const s16x8*)(qb + ks*32);
  }

  f32x4 oacc[8] = {};
  float m_r[4], l_r[4];
#pragma unroll
  for (int j = 0; j < 4; ++j) { m_r[j] = -3.0e38f; l_r[j] = 0.f; }

  // staging decomposition (per wave, per stage s)
  int krow_w = w*4 + fq;          // K row = s*16 + krow_w
  int kch    = fr;                // 16B chunk 0..15 within 256B K row
  int vrow_w = w*8 + (lane >> 3); // V row = s*32 + vrow_w
  int vch    = lane & 7;          // 16B chunk 0..7 within 128B V row

  int nkb = qt + 1;
  for (int kb = 0; kb < nkb; ++kb) {
    int kv0 = kb * 64;
    __syncthreads();   // prev iteration's reads done before overwrite
#pragma unroll
    for (int s = 0; s < 4; ++s) {
      int r = s*16 + krow_w;
      gload_lds16(qkv + (size_t)(b*SEQ + kv0 + r)*QKVC + D_MODEL
                      + ((kch ^ (r & 7)) * 8),
                  (char*)Kl + s*4096 + w*1024);
      int d = s*32 + vrow_w;
      gload_lds16(VT + (size_t)(b*DH + d)*SEQ + kv0 + ((vch ^ (d & 7)) * 8),
                  (char*)Vl + s*4096 + w*1024);
    }
    __syncthreads();   // drains vmcnt -> tiles ready

    // QK^T: S[16 q][64 kv] per wave
    f32x4 sfr[4] = {};
#pragma unroll
    for (int nt = 0; nt < 4; ++nt) {
      int row = nt*16 + fr;
#pragma unroll
      for (int ks = 0; ks < 4; ++ks) {
        int swz = (fq + ks*4) ^ (fr & 7);
        s16x8 kf = *(const s16x8*)&Kl[row*128 + swz*8];
        sfr[nt] = mfma16(qf[ks], kf, sfr[nt]);
      }
    }

    // scale + causal mask (only diagonal tile can violate causality)
    bool need_mask = (kb == nkb - 1);
#pragma unroll
    for (int nt = 0; nt < 4; ++nt) {
      int col = kv0 + nt*16 + fr;
#pragma unroll
      for (int j = 0; j < 4; ++j) {
        float v = sfr[nt][j] * scale;
        if (need_mask && col > q0 + fq*4 + j) v = -1.0e30f;
        sfr[nt][j] = v;
      }
    }

    // online softmax: reduce over 4 nt in-register + 16 lanes (fr)
    float fac[4];
#pragma unroll
    for (int j = 0; j < 4; ++j) {
      float pm = fmaxf(fmaxf(sfr[0][j], sfr[1][j]),
                       fmaxf(sfr[2][j], sfr[3][j]));
#pragma unroll
      for (int msk = 1; msk < 16; msk <<= 1)
        pm = fmaxf(pm, __shfl_xor(pm, msk, 16));
      float mnew = fmaxf(m_r[j], pm);
      fac[j] = __expf(m_r[j] - mnew);
      m_r[j] = mnew;
      float rs = 0.f;
#pragma unroll
      for (int nt = 0; nt < 4; ++nt) {
        float p = __expf(sfr[nt][j] - mnew);
        sfr[nt][j] = p;
        rs += p;
      }
#pragma unroll
      for (int msk = 1; msk < 16; msk <<= 1)
        rs += __shfl_xor(rs, msk, 16);
      l_r[j] = l_r[j] * fac[j] + rs;
    }
#pragma unroll
    for (int n2 = 0; n2 < 8; ++n2)
#pragma unroll
      for (int j = 0; j < 4; ++j) oacc[n2][j] *= fac[j];

    // P (C layout) -> per-wave LDS -> A-operand layout (no block barrier)
#pragma unroll
    for (int nt = 0; nt < 4; ++nt)
#pragma unroll
      for (int j = 0; j < 4; ++j)
        Pw[(fq*4 + j)*72 + nt*16 + fr] = f2bf(sfr[nt][j]);
    s16x8 pa[2];
#pragma unroll
    for (int ks = 0; ks < 2; ++ks)
      pa[ks] = *(const s16x8*)&Pw[fr*72 + fq*8 + ks*32];

    // PV: B-operand from swizzled Vl
#pragma unroll
    for (int n2 = 0; n2 < 8; ++n2) {
      int d = n2*16 + fr;
#pragma unroll
      for (int ks = 0; ks < 2; ++ks) {
        int swz = (fq + ks*4) ^ (fr & 7);
        s16x8 vf = *(const s16x8*)&Vl[d*64 + swz*8];
        oacc[n2] = mfma16(pa[ks], vf, oacc[n2]);
      }
    }
  }

  float inv[4];
#pragma unroll
  for (int j = 0; j < 4; ++j) inv[j] = 1.0f / l_r[j];
#pragma unroll
  for (int n2 = 0; n2 < 8; ++n2) {
    int col = h*DH + n2*16 + fr;
#pragma unroll
    for (int j = 0; j < 4; ++j) {
      int row = q0 + fq*4 + j;
      O[(size_t)(b*SEQ + row)*D_MODEL + col] = f2bf(oacc[n2][j] * inv[j]);
    }
  }
}

extern "C" void kernel_launch(void* const* d_in, const int* in_sizes, int n_in,
                              void* d_out, int out_size, void* d_ws, size_t ws_size,
                              hipStream_t stream) {
  const float* x     = (const float*)d_in[0];
  const float* W_qkv = (const float*)d_in[1];
  const float* b_qkv = (const float*)d_in[2];
  const float* W_out = (const float*)d_in[3];
  const float* b_out = (const float*)d_in[4];
  float* out = (float*)d_out;

  unsigned short* x_bf = (unsigned short*)d_ws;
  unsigned short* WqT  = x_bf + (size_t)MROWS * D_MODEL;
  unsigned short* WoT  = WqT  + (size_t)QKVC * D_MODEL;
  unsigned short* qkvb = WoT  + (size_t)D_MODEL * D_MODEL;
  unsigned short* VTb  = qkvb + (size_t)MROWS * QKVC;
  unsigned short* Ob   = VTb  + (size_t)BATCH * DH * SEQ;

  dim3 tb(32, 8);
  cvt_bf16_kernel<<<2048, 256, 0, stream>>>(x, x_bf, (MROWS * D_MODEL) / 4);
  transpose_cvt_kernel<<<dim3(QKVC/32, D_MODEL/32), tb, 0, stream>>>(W_qkv, WqT, D_MODEL, QKVC);
  transpose_cvt_kernel<<<dim3(D_MODEL/32, D_MODEL/32), tb, 0, stream>>>(W_out, WoT, D_MODEL, D_MODEL);

  gemm_bt_kernel<0><<<dim3(QKVC/128, MROWS/128), 256, 0, stream>>>(
      x_bf, WqT, b_qkv, qkvb, MROWS, QKVC, D_MODEL);

  transpose_v_kernel<<<dim3(SEQ/32, DH/32, BATCH), tb, 0, stream>>>(qkvb, VTb);

  mqa_attn_kernel<<<dim3(SEQ/64, NH, BATCH), 256, 0, stream>>>(qkvb, VTb, Ob);

  gemm_bt_kernel<1><<<dim3(D_MODEL/128, MROWS/128), 256, 0, stream>>>(
      Ob, WoT, b_out, out, MROWS, D_MODEL, D_MODEL);
}

// Round 3
// 223.841 us; speedup vs baseline: 2.2465x; 1.3730x over previous
//
#include <hip/hip_runtime.h>

#define D_MODEL 2048
#define QKVC 2304
#define DH 128
#define NH 16
#define BATCH 2
#define SEQ 2048
#define MROWS (BATCH*SEQ)   // 4096

typedef __attribute__((ext_vector_type(4))) float f32x4;
typedef __attribute__((ext_vector_type(16))) float f32x16;
typedef __attribute__((ext_vector_type(8))) short s16x8;
typedef __attribute__((ext_vector_type(8))) __bf16 bf16x8;
typedef __attribute__((ext_vector_type(4))) unsigned int u32x4;

static __device__ __forceinline__ unsigned short f2bf(float f) {
  unsigned int u = __builtin_bit_cast(unsigned int, f);
  u += 0x7fff + ((u >> 16) & 1);   // round-to-nearest-even
  return (unsigned short)(u >> 16);
}

static __device__ __forceinline__ unsigned int pkbf(float a, float b) {
  unsigned short x = __builtin_bit_cast(unsigned short, (__bf16)a);
  unsigned short y = __builtin_bit_cast(unsigned short, (__bf16)b);
  return (unsigned int)x | ((unsigned int)y << 16);
}

static __device__ __forceinline__ f32x4 mfma16(s16x8 a, s16x8 b, f32x4 c) {
  return __builtin_amdgcn_mfma_f32_16x16x32_bf16(
      __builtin_bit_cast(bf16x8, a), __builtin_bit_cast(bf16x8, b), c, 0, 0, 0);
}

static __device__ __forceinline__ f32x16 mfma32(s16x8 a, s16x8 b, f32x16 c) {
  return __builtin_amdgcn_mfma_f32_32x32x16_bf16(
      __builtin_bit_cast(bf16x8, a), __builtin_bit_cast(bf16x8, b), c, 0, 0, 0);
}

typedef const __attribute__((address_space(1))) void gvoid_t;
typedef __attribute__((address_space(3))) void svoid_t;

static __device__ __forceinline__ void gload_lds16(const void* g, void* l) {
  __builtin_amdgcn_global_load_lds((gvoid_t*)g, (svoid_t*)l, 16, 0, 0);
}

// ---------------- fp32 -> bf16 elementwise (x) ----------------
__global__ void cvt_bf16_kernel(const float* __restrict__ in,
                                unsigned short* __restrict__ out, int n4) {
  int i = blockIdx.x * blockDim.x + threadIdx.x;
  int stride = gridDim.x * blockDim.x;
  for (int idx = i; idx < n4; idx += stride) {
    float4 v = ((const float4*)in)[idx];
    ushort4 o;
    o.x = f2bf(v.x); o.y = f2bf(v.y); o.z = f2bf(v.z); o.w = f2bf(v.w);
    ((ushort4*)out)[idx] = o;
  }
}

// ------------- transpose+convert: f32 [R][C] -> bf16 [C][R] -------------
__global__ void transpose_cvt_kernel(const float* __restrict__ in,
                                     unsigned short* __restrict__ out,
                                     int R, int C) {
  __shared__ float tile[32][33];
  int c0 = blockIdx.x * 32, r0 = blockIdx.y * 32;
  int tx = threadIdx.x, ty = threadIdx.y;
#pragma unroll
  for (int i = 0; i < 4; ++i)
    tile[ty + i*8][tx] = in[(size_t)(r0 + ty + i*8) * C + c0 + tx];
  __syncthreads();
#pragma unroll
  for (int i = 0; i < 4; ++i)
    out[(size_t)(c0 + ty + i*8) * R + r0 + tx] = f2bf(tile[tx][ty + i*8]);
}

// ------------- transpose V: VT[b][d][s] = qkv[b*S+s][2176+d] -------------
__global__ void transpose_v_kernel(const unsigned short* __restrict__ qkv,
                                   unsigned short* __restrict__ VT) {
  __shared__ unsigned short tile[32][33];
  int s0 = blockIdx.x * 32, d0 = blockIdx.y * 32, b = blockIdx.z;
  int tx = threadIdx.x, ty = threadIdx.y;
#pragma unroll
  for (int i = 0; i < 4; ++i)
    tile[ty + i*8][tx] =
        qkv[(size_t)(b*SEQ + s0 + ty + i*8) * QKVC + (D_MODEL + DH) + d0 + tx];
  __syncthreads();
#pragma unroll
  for (int i = 0; i < 4; ++i)
    VT[(size_t)(b*DH + d0 + ty + i*8) * SEQ + s0 + tx] = tile[tx][ty + i*8];
}

// ------------- GEMM: C[M,N] = A[M,K](bf16) * BT[N,K]^T(bf16) + bias -------------
template<int OUT_F32>
__global__ __launch_bounds__(256, 2)
void gemm_bt_kernel(const unsigned short* __restrict__ A,
                    const unsigned short* __restrict__ BT,
                    const float* __restrict__ bias,
                    void* __restrict__ Cout,
                    int M, int N, int K) {
  __shared__ unsigned short Al[128*32];
  __shared__ unsigned short Bl[128*32];
  int tid = threadIdx.x;
  int lane = tid & 63, wave = tid >> 6;
  int m0 = blockIdx.y * 128, n0 = blockIdx.x * 128;
  int wr = wave >> 1, wc = wave & 1;
  int fr = lane & 15, fq = lane >> 4;
  f32x4 acc[4][4] = {};

  int c0 = wave * 2;
  int kcol = (lane & 3) * 8;
  int rsub = (lane >> 2);

  for (int k0 = 0; k0 < K; k0 += 32) {
#pragma unroll
    for (int i = 0; i < 2; ++i) {
      int c = c0 + i;
      int row = c*16 + rsub;
      gload_lds16(A  + (size_t)(m0 + row)*K + k0 + kcol, (char*)Al + c*1024);
      gload_lds16(BT + (size_t)(n0 + row)*K + k0 + kcol, (char*)Bl + c*1024);
    }
    __syncthreads();
    s16x8 af[4], bfr[4];
#pragma unroll
    for (int m = 0; m < 4; ++m)
      af[m] = *(const s16x8*)&Al[(wr*64 + m*16 + fr)*32 + fq*8];
#pragma unroll
    for (int n = 0; n < 4; ++n)
      bfr[n] = *(const s16x8*)&Bl[(wc*64 + n*16 + fr)*32 + fq*8];
#pragma unroll
    for (int m = 0; m < 4; ++m)
#pragma unroll
      for (int n = 0; n < 4; ++n)
        acc[m][n] = mfma16(af[m], bfr[n], acc[m][n]);
    __syncthreads();
  }

#pragma unroll
  for (int n = 0; n < 4; ++n) {
    int col = n0 + wc*64 + n*16 + fr;
    float bv = bias[col];
#pragma unroll
    for (int m = 0; m < 4; ++m) {
      int rowb = m0 + wr*64 + m*16 + fq*4;
#pragma unroll
      for (int j = 0; j < 4; ++j) {
        float v = acc[m][n][j] + bv;
        if (OUT_F32) ((float*)Cout)[(size_t)(rowb + j)*N + col] = v;
        else ((unsigned short*)Cout)[(size_t)(rowb + j)*N + col] = f2bf(v);
      }
    }
  }
}

// ------------- causal MQA attention, 32x32 MFMA, swapped QK^T -------------
// Block: 256 threads = 4 waves; QBLK=128 (32 q-rows/wave). KVBLK=64.
// S^T = mfma32(K,Q): lane (fr=l&31, hi=l>>5) owns q-row fr; kv = crow(r,hi).
// Softmax per-lane scalar m/l + one shfl_xor(32). P->A-frag via pack+shfl.
// K/V double-buffered in LDS (XOR-swizzled), ONE barrier per KVBLK.
__global__ __launch_bounds__(256, 2)
void mqa_attn_kernel(const unsigned short* __restrict__ qkv,
                     const unsigned short* __restrict__ VT,
                     unsigned short* __restrict__ O) {
  __shared__ unsigned short Kl[2][64*128];    // 2 x 16 KB
  __shared__ unsigned short Vl[2][128*64];    // 2 x 16 KB
  int qt = (gridDim.x - 1) - blockIdx.x;      // longest blocks first
  int h = blockIdx.y, b = blockIdx.z;
  int tid = threadIdx.x;
  int lane = tid & 63, wid = tid >> 6;
  int fr = lane & 31, hi = lane >> 5;
  int q0 = qt*128 + wid*32;                   // wave's q base
  const float scale = 0.08838834764831845f;   // 1/sqrt(128)

  // Q fragment (B-operand): col=q=q0+fr, k = d = s*16 + hi*8 + 0..7
  s16x8 qf[8];
  {
    const unsigned short* qb =
        qkv + (size_t)(b*SEQ + q0 + fr)*QKVC + h*DH + hi*8;
#pragma unroll
    for (int s = 0; s < 8; ++s) qf[s] = *(const s16x8*)(qb + s*16);
  }

  f32x16 oacc[4] = {};
  float m_r = -3.0e38f, l_r = 0.f;

  int nkb = 2*(qt + 1);
  int last_act = (q0 + 31) >> 6;   // last KVBLK this wave computes

  // ---- staging: 4 iters x (1 K-chunk + 1 V-chunk) of 16B per thread ----
  // K tile [64][128]: idx = i*256+tid -> row=idx>>4, chunk c=idx&15 (16B)
  //   LDS[row][c] = global[row][c ^ (row&7)]  (linear LDS dest, swz source)
  // V tile [128][64]: d=idx>>3, c=idx&7; LDS[d][c] = global[d][c ^ (d&7)]
#define STAGE(kb_, buf_) do {                                              \
    int kv0_ = (kb_)*64;                                                   \
    _Pragma("unroll")                                                      \
    for (int i_ = 0; i_ < 4; ++i_) {                                       \
      int idx_ = i_*256 + tid;                                             \
      int r_ = idx_ >> 4, c_ = idx_ & 15;                                  \
      gload_lds16(qkv + (size_t)(b*SEQ + kv0_ + r_)*QKVC + D_MODEL         \
                      + ((c_ ^ (r_ & 7)) * 8),                             \
                  (char*)&Kl[buf_][0] + (size_t)idx_*16);                  \
      int d_ = idx_ >> 3, c2_ = idx_ & 7;                                  \
      gload_lds16(VT + (size_t)(b*DH + d_)*SEQ + kv0_ + ((c2_ ^ (d_ & 7))*8), \
                  (char*)&Vl[buf_][0] + (size_t)idx_*16);                  \
    }                                                                      \
  } while (0)

  STAGE(0, 0);
  __syncthreads();

  for (int kb = 0; kb < nkb; ++kb) {
    int cur = kb & 1;
    if (kb + 1 < nkb) STAGE(kb + 1, cur ^ 1);

    if (kb <= last_act) {
      const unsigned short* Kb = &Kl[cur][0];
      const unsigned short* Vb = &Vl[cur][0];
      int kv0 = kb*64;

      // ---- QK^T (swapped): sfr[t] = S^T tile, D[row=kv][col=q] ----
      f32x16 sfr[2] = {};
#pragma unroll
      for (int t = 0; t < 2; ++t) {
        int row = t*32 + fr;
#pragma unroll
        for (int s = 0; s < 8; ++s) {
          int cc = (s*2 + hi) ^ (fr & 7);
          s16x8 kf = *(const s16x8*)&Kb[row*128 + cc*8];
          sfr[t] = mfma32(kf, qf[s], sfr[t]);
        }
      }

      // ---- scale + causal mask ----
      bool need_mask = (kv0 + 63 > q0);
      int q = q0 + fr;
#pragma unroll
      for (int t = 0; t < 2; ++t)
#pragma unroll
        for (int r = 0; r < 16; ++r) {
          float v = sfr[t][r] * scale;
          if (need_mask) {
            int kv = kv0 + t*32 + (r & 3) + 8*(r >> 2) + 4*hi;
            if (kv > q) v = -1.0e30f;
          }
          sfr[t][r] = v;
        }

      // ---- online softmax: per-lane row, 1 cross-lane step ----
      float pm = sfr[0][0];
#pragma unroll
      for (int t = 0; t < 2; ++t)
#pragma unroll
        for (int r = 0; r < 16; ++r) pm = fmaxf(pm, sfr[t][r]);
      pm = fmaxf(pm, __shfl_xor(pm, 32));

      bool stable = __all(pm <= m_r + 8.0f) != 0;   // defer-max (T13)
      float fac = 1.0f;
      if (!stable) { fac = __expf(m_r - fmaxf(m_r, pm)); m_r = fmaxf(m_r, pm); }

      float rs = 0.f;
#pragma unroll
      for (int t = 0; t < 2; ++t)
#pragma unroll
        for (int r = 0; r < 16; ++r) {
          float p = __expf(sfr[t][r] - m_r);
          sfr[t][r] = p;
          rs += p;
        }
      rs += __shfl_xor(rs, 32);
      l_r = l_r * fac + rs;

      if (!stable) {
#pragma unroll
        for (int r = 0; r < 16; ++r) {
          int src = (r & 3) + 8*(r >> 2) + 4*hi;
          float fv = __shfl(fac, src);
#pragma unroll
          for (int n2 = 0; n2 < 4; ++n2) oacc[n2][r] *= fv;
        }
      }

      // ---- P -> A-fragments in-register (pack + shfl_xor 32) + PV ----
#pragma unroll
      for (int t = 0; t < 2; ++t) {
        s16x8 pa[2];
#pragma unroll
        for (int ks = 0; ks < 2; ++ks) {
          unsigned int X0 = pkbf(sfr[t][8*ks+0], sfr[t][8*ks+1]);
          unsigned int X1 = pkbf(sfr[t][8*ks+2], sfr[t][8*ks+3]);
          unsigned int Y0 = pkbf(sfr[t][8*ks+4], sfr[t][8*ks+5]);
          unsigned int Y1 = pkbf(sfr[t][8*ks+6], sfr[t][8*ks+7]);
          unsigned int s0 = __shfl_xor(hi ? X0 : Y0, 32);
          unsigned int s1 = __shfl_xor(hi ? X1 : Y1, 32);
          u32x4 pw;
          pw[0] = hi ? s0 : X0;   // k pair 0,1
          pw[1] = hi ? s1 : X1;   // k pair 2,3
          pw[2] = hi ? Y0 : s0;   // k pair 4,5
          pw[3] = hi ? Y1 : s1;   // k pair 6,7
          pa[ks] = __builtin_bit_cast(s16x8, pw);
        }
#pragma unroll
        for (int n2 = 0; n2 < 4; ++n2) {
          int d = n2*32 + fr;
#pragma unroll
          for (int ks = 0; ks < 2; ++ks) {
            int cc = (t*4 + ks*2 + hi) ^ (d & 7);
            s16x8 vf = *(const s16x8*)&Vb[d*64 + cc*8];
            oacc[n2] = mfma32(pa[ks], vf, oacc[n2]);
          }
        }
      }
    }
    __syncthreads();   // drains stage(kb+1) vmcnt + releases buf swap
  }

  // ---- epilogue: normalize + store ----
  float invl = 1.0f / l_r;
#pragma unroll
  for (int r = 0; r < 16; ++r) {
    int qrow = (r & 3) + 8*(r >> 2) + 4*hi;
    float iv = __shfl(invl, qrow);
    size_t rowoff = (size_t)(b*SEQ + q0 + qrow)*D_MODEL + h*DH;
#pragma unroll
    for (int n2 = 0; n2 < 4; ++n2)
      O[rowoff + n2*32 + fr] = f2bf(oacc[n2][r] * iv);
  }
#undef STAGE
}

extern "C" void kernel_launch(void* const* d_in, const int* in_sizes, int n_in,
                              void* d_out, int out_size, void* d_ws, size_t ws_size,
                              hipStream_t stream) {
  const float* x     = (const float*)d_in[0];
  const float* W_qkv = (const float*)d_in[1];
  const float* b_qkv = (const float*)d_in[2];
  const float* W_out = (const float*)d_in[3];
  const float* b_out = (const float*)d_in[4];
  float* out = (float*)d_out;

  unsigned short* x_bf = (unsigned short*)d_ws;
  unsigned short* WqT  = x_bf + (size_t)MROWS * D_MODEL;
  unsigned short* WoT  = WqT  + (size_t)QKVC * D_MODEL;
  unsigned short* qkvb = WoT  + (size_t)D_MODEL * D_MODEL;
  unsigned short* VTb  = qkvb + (size_t)MROWS * QKVC;
  unsigned short* Ob   = VTb  + (size_t)BATCH * DH * SEQ;

  dim3 tb(32, 8);
  cvt_bf16_kernel<<<2048, 256, 0, stream>>>(x, x_bf, (MROWS * D_MODEL) / 4);
  transpose_cvt_kernel<<<dim3(QKVC/32, D_MODEL/32), tb, 0, stream>>>(W_qkv, WqT, D_MODEL, QKVC);
  transpose_cvt_kernel<<<dim3(D_MODEL/32, D_MODEL/32), tb, 0, stream>>>(W_out, WoT, D_MODEL, D_MODEL);

  gemm_bt_kernel<0><<<dim3(QKVC/128, MROWS/128), 256, 0, stream>>>(
      x_bf, WqT, b_qkv, qkvb, MROWS, QKVC, D_MODEL);

  transpose_v_kernel<<<dim3(SEQ/32, DH/32, BATCH), tb, 0, stream>>>(qkvb, VTb);

  mqa_attn_kernel<<<dim3(SEQ/128, NH, BATCH), 256, 0, stream>>>(qkvb, VTb, Ob);

  gemm_bt_kernel<1><<<dim3(D_MODEL/128, MROWS/128), 256, 0, stream>>>(
      Ob, WoT, b_out, out, MROWS, D_MODEL, D_MODEL);
}